// Round 7
// baseline (165.948 us; speedup 1.0000x reference)
//
#include <hip/hip_runtime.h>

#define T_DIM 720
#define B_DIM 50000

#define OFF_SEAS (T_DIM * B_DIM)                  /* 36,000,000 */
#define SEAS_ROWS 727
#define OFF_MSLD (OFF_SEAS + SEAS_ROWS * B_DIM)   /* 72,350,000 */
#define N_MSLD 718

#define NBLK 782                                  /* ceil(50000/64) 1-wave blocks */
#define NW NBLK

// Wave64 sum via DPP (VALU-only, no DS): row_shr 1/2/4/8 then row_bcast 15/31.
// Total lands in lane 63. old=0 is the add-identity for masked-off lanes.
__device__ __forceinline__ float dpp_sum64(float v) {
#define DPP_ADD_STAGE(CTRL, RMASK)                                             \
  v += __int_as_float(__builtin_amdgcn_update_dpp(0, __float_as_int(v),        \
                                                  CTRL, RMASK, 0xf, false));
  DPP_ADD_STAGE(0x111, 0xf)  // row_shr:1
  DPP_ADD_STAGE(0x112, 0xf)  // row_shr:2
  DPP_ADD_STAGE(0x114, 0xf)  // row_shr:4
  DPP_ADD_STAGE(0x118, 0xf)  // row_shr:8
  DPP_ADD_STAGE(0x142, 0xa)  // row_bcast:15 -> rows 1,3
  DPP_ADD_STAGE(0x143, 0xc)  // row_bcast:31 -> rows 2,3
#undef DPP_ADD_STAGE
  return v;
}

// One recurrence step. POS compile-time so buf/queues stay in registers.
// Stores are REGULAR (retire at L2 accept), not nontemporal: NT stores retire
// at HBM latency and throttle the wave through the 63-deep vmcnt FIFO.
#define ESRNN_STEP(QB, POS)                                                    \
  {                                                                            \
    float x = QB[POS];                                                         \
    float s = buf[POS];                                                        \
    float nl = fmaf(lsm, __fdividef(x, s), olm * lev);                         \
    float ll = __logf(nl);                                                     \
    float ld = ll - llev;                                                      \
    float ns = fmaf(ssm, __fdividef(x, nl), osm * s);                          \
    buf[POS] = ns;                                                             \
    if (valid) {                                                               \
      *levs_ptr = nl;                                                          \
      *seas_ptr = ns;                                                          \
    }                                                                          \
    levs_ptr += B_DIM;                                                         \
    seas_ptr += B_DIM;                                                         \
    float d = ld - pld;                                                        \
    float sq = (valid && t >= 2) ? d * d : 0.0f;                               \
    float tot = dpp_sum64(sq);                                                 \
    if (lane == 63 && t >= 2) *pptr = tot;                                     \
    pptr += NW;                                                                \
    pld = ld;                                                                  \
    llev = ll;                                                                 \
    lev = nl;                                                                  \
    ++t;                                                                       \
  }

// Prefetch group G (rows 1+7G .. 7+7G, clamped) into QB. NT loads: read-once
// stream, don't pollute L2 (which the store path uses as a combining buffer).
#define PREFETCH(QB, G)                                                        \
  {                                                                            \
    int tp = 1 + 7 * (G);                                                      \
    _Pragma("unroll") for (int j = 0; j < 7; ++j) {                            \
      int r = tp + j;                                                          \
      r = r > 719 ? 719 : r;                                                   \
      QB[j] = __builtin_nontemporal_load(&train[r * B_DIM + bc]);              \
    }                                                                          \
  }

#define ESRNN_GROUP(QB, QP)                                                    \
  {                                                                            \
    PREFETCH(QP, g + 2)                                                        \
    ESRNN_STEP(QB, 0)                                                          \
    ESRNN_STEP(QB, 1)                                                          \
    ESRNN_STEP(QB, 2)                                                          \
    ESRNN_STEP(QB, 3)                                                          \
    ESRNN_STEP(QB, 4)                                                          \
    ESRNN_STEP(QB, 5)                                                          \
    ESRNN_STEP(QB, 6)                                                          \
    ++g;                                                                       \
  }

__global__ __launch_bounds__(64) void esrnn_main(
    const float* __restrict__ train,        // (720, B)
    const float* __restrict__ lev_sms,      // (B,)
    const float* __restrict__ seas_sms,     // (B,)
    const float* __restrict__ init_seas_in, // (B, 7)
    float* __restrict__ levs_out,           // (720, B)
    float* __restrict__ seas_out,           // (727, B)
    float* __restrict__ partial)            // (718, NW) per-wave partials
{
  int b = blockIdx.x * 64 + threadIdx.x;
  bool valid = (b < B_DIM);
  int bc = valid ? b : (B_DIM - 1);
  int lane = threadIdx.x;
  int wid = blockIdx.x;

  float lsm = 1.0f / (1.0f + __expf(-lev_sms[bc]));
  float ssm = 1.0f / (1.0f + __expf(-seas_sms[bc]));
  float olm = 1.0f - lsm;
  float osm = 1.0f - ssm;

  float is[7];
#pragma unroll
  for (int j = 0; j < 7; ++j) is[j] = __expf(init_seas_in[bc * 7 + j]);

  float seas0 = is[0];
  float x0 = train[bc];
  float lev = __fdividef(x0, seas0);

  if (valid) {
    levs_out[b] = lev;
#pragma unroll
    for (int j = 0; j < 7; ++j) seas_out[j * B_DIM + b] = is[j];
    seas_out[7 * B_DIM + b] = seas0;
  }

  float buf[7];
#pragma unroll
  for (int j = 0; j < 6; ++j) buf[j] = is[j + 1];
  buf[6] = seas0;

  float llev = __logf(lev);
  float pld = 0.0f;

  // Incremental output pointers (t starts at 1; partial row starts at t-2=-1,
  // guarded by the t>=2 condition until it's in range).
  float* levs_ptr = levs_out + (size_t)B_DIM + b;
  float* seas_ptr = seas_out + (size_t)8 * B_DIM + b;
  float* pptr = partial + wid - NW;  // becomes partial[0*NW+wid] at t=2

  float xa[7], xb[7], xc[7];
  int g = 0;
  int t = 1;
  PREFETCH(xa, 0)
  PREFETCH(xb, 1)

  // 102 groups = 34 x 3-phase buffer rotation, prefetching 2 groups ahead.
  for (int k = 0; k < 34; ++k) {
    ESRNN_GROUP(xa, xc)
    ESRNN_GROUP(xb, xa)
    ESRNN_GROUP(xc, xb)
  }

  // tail: t = 715..719 in xa (group 102, 102 % 3 == 0), buf pos 0..4
  ESRNN_STEP(xa, 0)
  ESRNN_STEP(xa, 1)
  ESRNN_STEP(xa, 2)
  ESRNN_STEP(xa, 3)
  ESRNN_STEP(xa, 4)
}

__global__ __launch_bounds__(64) void esrnn_reduce2(
    const float* __restrict__ partial, float* __restrict__ msld) {
  int row = blockIdx.x;  // 0..717
  int lane = threadIdx.x;
  float s = 0.0f;
  for (int i = lane; i < NW; i += 64) s += partial[row * NW + i];
  float tot = dpp_sum64(s);
  if (lane == 63) msld[row] = tot * (1.0f / (float)B_DIM);
}

extern "C" void kernel_launch(void* const* d_in, const int* in_sizes, int n_in,
                              void* d_out, int out_size, void* d_ws,
                              size_t ws_size, hipStream_t stream) {
  const float* train = (const float*)d_in[0];
  const float* lev_sms = (const float*)d_in[1];
  const float* seas_sms = (const float*)d_in[2];
  const float* init_seas = (const float*)d_in[3];

  float* out = (float*)d_out;
  float* levs = out;
  float* seas = out + OFF_SEAS;
  float* msld = out + OFF_MSLD;
  float* partial = (float*)d_ws;  // 718*782*4 ~= 2.25 MB

  esrnn_main<<<NBLK, 64, 0, stream>>>(train, lev_sms, seas_sms, init_seas,
                                      levs, seas, partial);
  esrnn_reduce2<<<N_MSLD, 64, 0, stream>>>(partial, msld);
}